// Round 13
// baseline (128.062 us; speedup 1.0000x reference)
//
#include <hip/hip_runtime.h>

typedef _Float16 f16x8 __attribute__((ext_vector_type(8)));
typedef _Float16 f16x4 __attribute__((ext_vector_type(4)));
typedef float f32x4 __attribute__((ext_vector_type(4)));

// ---------------------------------------------------------------------------
// K1a: blocks 0..767 (b x row-pair): transpose x -> xt16 (f16 hi) AND
//      xlo16 (f16 residual lo, bit-identical to K2's former in-kernel split),
//      write 2x2 avgpool (exact f32) into xsum.
//      blocks 768..783: weight prep (wfA/wfT/w_v_h/wsf) as before.
// ---------------------------------------------------------------------------
__global__ __launch_bounds__(256) void k1a_prep(
    const float* __restrict__ x, const float* __restrict__ w_f,
    const float* __restrict__ w_v, const float* __restrict__ w_skip,
    _Float16* __restrict__ xt16, _Float16* __restrict__ xlo16,
    float* __restrict__ xsum,
    _Float16* __restrict__ wfA, _Float16* __restrict__ wfT,
    _Float16* __restrict__ w_v_h, _Float16* __restrict__ wsf)
{
  const int bid = blockIdx.x;
  const int t = threadIdx.x;

  if (bid >= 768) {
    const int wb = bid - 768;         // 0..15
    for (int i = wb * 512 + t; i < wb * 512 + 512; i += 256) {
      int co = i >> 6, c = i & 63;
      float w = w_f[i];
      _Float16 hi = (_Float16)w, lo = (_Float16)(w - (float)hi);
      int laneA = (co & 15) | (((c >> 3) & 3) << 4);
      int jA = c >> 5;
      size_t oA = ((size_t)(co >> 4) * 4) * 512 + (size_t)laneA * 8 + (c & 7);
      wfA[oA + (size_t)jA * 512] = hi;
      wfA[oA + (size_t)(jA + 2) * 512] = lo;
      int laneT = (c & 15) | (((co >> 3) & 3) << 4);
      int jT = co >> 5;
      size_t oT = ((size_t)(c >> 4) * 8) * 512 + (size_t)laneT * 8 + (co & 7);
      wfT[oT + (size_t)jT * 512] = hi;
      wfT[oT + (size_t)(jT + 4) * 512] = lo;
    }
    for (int i = wb * 512 + t; i < wb * 512 + 512; i += 256)
      w_v_h[i] = (_Float16)w_v[i];
    for (int i = wb * 4608 + t; i < wb * 4608 + 4608; i += 256) {
      int co = i / 576, kk = i % 576;
      int dd = kk >> 6, c = kk & 63, dh = dd / 3, dw = dd % 3;
      int mb = co >> 4, ccol = co & 15;
      int ks = kk >> 5, g = (kk >> 3) & 3, e = kk & 7;
      size_t dst = (((size_t)mb * 18 + ks) * 64 + (ccol | (g << 4))) * 8 + e;
      wsf[dst] = (_Float16)w_skip[((co * 64 + c) * 3 + dh) * 3 + dw];
    }
    return;
  }

  const int b = bid / 48, rp = bid % 48;
  const int c = t >> 2, q = t & 3;
  __shared__ __align__(16) _Float16 xst[2 * 96 * 72];   // pitch 72 = 144 B
  __shared__ __align__(16) _Float16 xsl[2 * 96 * 72];

  float pool[12];
  #pragma unroll
  for (int p = 0; p < 12; ++p) pool[p] = 0.f;

  #pragma unroll
  for (int r = 0; r < 2; ++r) {
    const float* xr = x + ((size_t)(b * 64 + c) * 96 + 2 * rp + r) * 96 + q * 24;
    #pragma unroll
    for (int j2 = 0; j2 < 6; ++j2) {
      f32x4 v = *(const f32x4*)(xr + j2 * 4);
      #pragma unroll
      for (int u = 0; u < 4; ++u) {
        int C = q * 24 + j2 * 4 + u;
        _Float16 hi = (_Float16)v[u];
        xst[(r * 96 + C) * 72 + c] = hi;
        xsl[(r * 96 + C) * 72 + c] = (_Float16)(v[u] - (float)hi);
        pool[(j2 * 4 + u) >> 1] += v[u];
      }
    }
  }
  {
    const int f1 = rp >= 24 ? 1 : 0, wl = rp - f1 * 24;
    #pragma unroll
    for (int p = 0; p < 12; ++p) {
      int C = q * 24 + 2 * p;
      int f2 = C >= 48 ? 1 : 0;
      int m = wl * 24 + (C - f2 * 48) / 2;
      xsum[((size_t)(b * 4 + f1 * 2 + f2) * 576 + m) * 64 + c] = 0.25f * pool[p];
    }
  }
  __syncthreads();
  for (int i = t; i < 1536; i += 256) {
    int r = i / 768, rem = i % 768, col = rem >> 3, cg = rem & 7;
    size_t gdst = (((size_t)b * 96 + 2 * rp + r) * 96 + col) * 64 + cg * 8;
    *(f16x8*)(xt16 + gdst) = *(const f16x8*)&xst[(r * 96 + col) * 72 + cg * 8];
    *(f16x8*)(xlo16 + gdst) = *(const f16x8*)&xsl[(r * 96 + col) * 72 + cg * 8];
  }
}

// ---------------------------------------------------------------------------
// K1b: per (m-chunk of 96, bf): centers via MFMA (3-term hi/lo split),
//   in-register norm reduce, cenW written in K2's fragment-major layout.
// ---------------------------------------------------------------------------
__global__ __launch_bounds__(256) void k1b_centers(
    const float* __restrict__ xsum, const float* __restrict__ b_f,
    const _Float16* __restrict__ wfA, const _Float16* __restrict__ wfT,
    _Float16* __restrict__ cenW, float* __restrict__ dvec)
{
  const int mc = blockIdx.x;          // 0..5
  const int bf = blockIdx.y;          // 0..63
  const int m0 = mc * 96;
  const int t = threadIdx.x;
  const int lane = t & 63, wid = t >> 6;
  const int ccol = lane & 15, g = lane >> 4;

  __shared__ __align__(16) _Float16 cenT_h[96][136];
  __shared__ __align__(16) _Float16 cenT_l[96][136];
  __shared__ __align__(16) _Float16 xcs_h[96][72];
  __shared__ __align__(16) _Float16 xcs_l[96][72];
  float* part = (float*)&xcs_h[0][0];   // aliased after GEMM1 (sync-guarded)

  for (int i = t; i < 96 * 64; i += 256) {
    int m = i >> 6, c = i & 63;
    float s = xsum[((size_t)bf * 576 + m0 + m) * 64 + c];
    _Float16 hi = (_Float16)s;
    xcs_h[m][c] = hi;
    xcs_l[m][c] = (_Float16)(s - (float)hi);
  }
  __syncthreads();

  f32x4 acc[2][6];
  f32x4 bfv[2];
  #pragma unroll
  for (int cbi = 0; cbi < 2; ++cbi) {
    const int cb = wid + cbi * 4;
    bfv[cbi] = *(const f32x4*)(b_f + cb * 16 + g * 4);
    const _Float16* wa = wfA + (size_t)cb * 2048 + (size_t)lane * 8;
    f16x8 a0h = *(const f16x8*)(wa);
    f16x8 a1h = *(const f16x8*)(wa + 512);
    f16x8 a0l = *(const f16x8*)(wa + 1024);
    f16x8 a1l = *(const f16x8*)(wa + 1536);
    #pragma unroll
    for (int nb = 0; nb < 6; ++nb) {
      const int m = nb * 16 + ccol;
      f16x8 b0h = *(const f16x8*)&xcs_h[m][g * 8];
      f16x8 b1h = *(const f16x8*)&xcs_h[m][32 + g * 8];
      f16x8 b0l = *(const f16x8*)&xcs_l[m][g * 8];
      f16x8 b1l = *(const f16x8*)&xcs_l[m][32 + g * 8];
      f32x4 a2 = bfv[cbi];
      a2 = __builtin_amdgcn_mfma_f32_16x16x32_f16(a0h, b0h, a2, 0, 0, 0);
      a2 = __builtin_amdgcn_mfma_f32_16x16x32_f16(a1h, b1h, a2, 0, 0, 0);
      a2 = __builtin_amdgcn_mfma_f32_16x16x32_f16(a0h, b0l, a2, 0, 0, 0);
      a2 = __builtin_amdgcn_mfma_f32_16x16x32_f16(a1h, b1l, a2, 0, 0, 0);
      a2 = __builtin_amdgcn_mfma_f32_16x16x32_f16(a0l, b0h, a2, 0, 0, 0);
      a2 = __builtin_amdgcn_mfma_f32_16x16x32_f16(a1l, b1h, a2, 0, 0, 0);
      acc[cbi][nb] = a2;
    }
  }
  __syncthreads();   // all xcs reads complete; part may now alias it

  #pragma unroll
  for (int nb = 0; nb < 6; ++nb) {
    float ss = 0.f, db = 0.f;
    #pragma unroll
    for (int cbi = 0; cbi < 2; ++cbi)
      #pragma unroll
      for (int r = 0; r < 4; ++r) {
        float v = acc[cbi][nb][r];
        ss = fmaf(v, v, ss);
        db = fmaf(v, bfv[cbi][r], db);
      }
    #pragma unroll
    for (int off = 16; off <= 32; off <<= 1) {
      ss += __shfl_xor(ss, off, 64);
      db += __shfl_xor(db, off, 64);
    }
    if (lane < 16) {
      part[wid * 96 + nb * 16 + lane] = ss;
      part[384 + wid * 96 + nb * 16 + lane] = db;
    }
  }
  __syncthreads();
  if (t < 96) {
    float ss = part[t] + part[96 + t] + part[192 + t] + part[288 + t];
    float db = part[384 + t] + part[480 + t] + part[576 + t] + part[672 + t];
    float inv = 1.0f / fmaxf(sqrtf(ss), 1e-12f);
    part[768 + t] = inv;
    dvec[bf * 576 + m0 + t] = inv * db;
  }
  __syncthreads();

  #pragma unroll
  for (int nb = 0; nb < 6; ++nb) {
    const int m = nb * 16 + ccol;
    const float inv = part[768 + m];
    #pragma unroll
    for (int cbi = 0; cbi < 2; ++cbi) {
      const int cb = wid + cbi * 4;
      #pragma unroll
      for (int r = 0; r < 4; ++r) {
        float v = acc[cbi][nb][r] * inv;
        _Float16 hi = (_Float16)v;
        cenT_h[m][cb * 16 + g * 4 + r] = hi;
        cenT_l[m][cb * 16 + g * 4 + r] = (_Float16)(v - (float)hi);
      }
    }
  }
  __syncthreads();

  // GEMM2: wave wid owns c-block wid; B = wfT frags (global, coalesced)
  const _Float16* wt = wfT + (size_t)wid * 4096 + (size_t)lane * 8;
  f16x8 tbh[4], tbl[4];
  #pragma unroll
  for (int j2 = 0; j2 < 4; ++j2) {
    tbh[j2] = *(const f16x8*)(wt + j2 * 512);
    tbl[j2] = *(const f16x8*)(wt + (j2 + 4) * 512);
  }
  #pragma unroll 1
  for (int mb = 0; mb < 6; ++mb) {
    f16x8 tah[4], tal[4];
    #pragma unroll
    for (int j2 = 0; j2 < 4; ++j2) {
      tah[j2] = *(const f16x8*)&cenT_h[mb * 16 + ccol][j2 * 32 + g * 8];
      tal[j2] = *(const f16x8*)&cenT_l[mb * 16 + ccol][j2 * 32 + g * 8];
    }
    f32x4 a2 = {0.f, 0.f, 0.f, 0.f};
    #pragma unroll
    for (int j2 = 0; j2 < 4; ++j2) {
      a2 = __builtin_amdgcn_mfma_f32_16x16x32_f16(tah[j2], tbh[j2], a2, 0, 0, 0);
      a2 = __builtin_amdgcn_mfma_f32_16x16x32_f16(tah[j2], tbl[j2], a2, 0, 0, 0);
      a2 = __builtin_amdgcn_mfma_f32_16x16x32_f16(tal[j2], tbh[j2], a2, 0, 0, 0);
    }
    const int c = wid * 16 + ccol;
    const int lane2g = ((c >> 3) & 3) << 4;
    const int j2f = c >> 5, e = c & 7;
    #pragma unroll
    for (int r = 0; r < 4; ++r) {
      float v = a2[r];
      _Float16 hi = (_Float16)v;
      _Float16 lo = (_Float16)(v - (float)hi);
      size_t base = (((size_t)bf * 36 + mc * 6 + mb) * 4) * 512
                  + (size_t)((g * 4 + r) | lane2g) * 8 + e;
      cenW[base + (size_t)j2f * 512] = hi;
      cenW[base + (size_t)(j2f + 2) * 512] = lo;
    }
  }
}

// ---------------------------------------------------------------------------
// K2: per (bf, tile of 128 points): argmax via 3-term split f16 MFMA.
//   B fragments loaded DIRECTLY from xt16/xlo16 (c-contiguous layout: each
//   n-block = one contiguous 2KB row -> fully coalesced; no LDS staging, no
//   VALU hi/lo split). Gather reads hi-only from xt16 (om is f16-quantized;
//   5e-4 relative error << 0.159 threshold). LDS ~6KB -> residency no longer
//   LDS-capped. Chain-accumulate MFMA, strict-> argmax, 2-deep A ping-pong.
// ---------------------------------------------------------------------------
__global__ __launch_bounds__(256, 4) void k2_assign(
    const _Float16* __restrict__ xt16, const _Float16* __restrict__ xlo16,
    const _Float16* __restrict__ cenW,
    const float* __restrict__ dvec,
    float* __restrict__ xsum, float* __restrict__ counts)
{
  const int id = blockIdx.x;          // 0..1151
  const int xcd = id & 7;
  const int j = id >> 3;              // 0..143
  const int bf = xcd * 8 + j / 18;
  const int tile = j % 18;
  const int b = bf >> 2, f1 = (bf >> 1) & 1, f2 = bf & 1;
  const int t = threadIdx.x;
  const int lane = t & 63, wid = t >> 6;

  const int tr = tile / 3, tc = tile % 3;
  const int w0 = tr * 8, h0 = tc * 16;

  __shared__ __align__(16) float dvl[576];
  __shared__ float wbv[4][64];
  __shared__ int   wbi[4][64];
  __shared__ int   idxf[128];
  __shared__ int   olist[128];
  __shared__ int   ocnt;

  if (t == 0) ocnt = 0;
  for (int i = t; i < 576; i += 256) dvl[i] = dvec[bf * 576 + i];

  const int ccol = lane & 15;
  const int g = lane >> 4;
  const int half = wid >> 1;          // mb half (0: 0..17, 1: 18..35)
  const int nbh = wid & 1;            // n-block half (0: n<64, 1: n>=64)

  // tile base in xt16/xlo16: [b][R][C][c], R stride = 96*64 = 6144 elems
  const size_t tbase = (((size_t)b * 96 + f1 * 48 + w0) * 96 + f2 * 48 + h0) * 64;
  const _Float16* th = xt16 + tbase;
  const _Float16* tl = xlo16 + tbase;

  // B fragments: one contiguous 2KB row per n-block, coalesced f16x8 loads
  f16x8 Bh0[4], Bh1[4], Bl0[4], Bl1[4];
  #pragma unroll
  for (int q = 0; q < 4; ++q) {
    const size_t po = (size_t)(nbh * 4 + q) * 6144 + (size_t)ccol * 64 + g * 8;
    Bh0[q] = *(const f16x8*)(th + po);
    Bh1[q] = *(const f16x8*)(th + po + 32);
    Bl0[q] = *(const f16x8*)(tl + po);
    Bl1[q] = *(const f16x8*)(tl + po + 32);
  }
  __syncthreads();   // dvl ready (B-build needed no LDS)

  const int mb0 = half * 18;
  const _Float16* abase = cenW + (size_t)bf * 73728 + (size_t)mb0 * 2048
                        + (size_t)lane * 8;

  float bv[4];
  int bi[4];
  #pragma unroll
  for (int q = 0; q < 4; ++q) { bv[q] = -3.0e38f; bi[q] = 0; }

  f16x8 aA0 = *(const f16x8*)(abase);
  f16x8 aA1 = *(const f16x8*)(abase + 512);
  f16x8 aA2 = *(const f16x8*)(abase + 1024);
  f16x8 aA3 = *(const f16x8*)(abase + 1536);
  f16x8 aB0, aB1, aB2, aB3;

#define K2_BODY(kk, A0, A1, A2, A3)                                          \
  {                                                                          \
    const int mb = mb0 + (kk);                                               \
    f32x4 dv4 = *(const f32x4*)&dvl[mb * 16 + g * 4];                        \
    _Pragma("unroll")                                                        \
    for (int q = 0; q < 4; ++q) {                                            \
      f32x4 a4 = dv4;                                                        \
      a4 = __builtin_amdgcn_mfma_f32_16x16x32_f16(A0, Bh0[q], a4, 0, 0, 0);  \
      a4 = __builtin_amdgcn_mfma_f32_16x16x32_f16(A1, Bh1[q], a4, 0, 0, 0);  \
      a4 = __builtin_amdgcn_mfma_f32_16x16x32_f16(A0, Bl0[q], a4, 0, 0, 0);  \
      a4 = __builtin_amdgcn_mfma_f32_16x16x32_f16(A1, Bl1[q], a4, 0, 0, 0);  \
      a4 = __builtin_amdgcn_mfma_f32_16x16x32_f16(A2, Bh0[q], a4, 0, 0, 0);  \
      a4 = __builtin_amdgcn_mfma_f32_16x16x32_f16(A3, Bh1[q], a4, 0, 0, 0);  \
      _Pragma("unroll")                                                      \
      for (int r = 0; r < 4; ++r) {                                          \
        float vv = a4[r];                                                    \
        if (vv > bv[q]) { bv[q] = vv; bi[q] = mb * 16 + g * 4 + r; }         \
      }                                                                      \
    }                                                                        \
  }

  #pragma unroll 1
  for (int k = 0; k < 18; k += 2) {
    const _Float16* nb1 = abase + (size_t)(k + 1) * 2048;
    aB0 = *(const f16x8*)(nb1);
    aB1 = *(const f16x8*)(nb1 + 512);
    aB2 = *(const f16x8*)(nb1 + 1024);
    aB3 = *(const f16x8*)(nb1 + 1536);
    K2_BODY(k, aA0, aA1, aA2, aA3);
    const int kn = (k + 2 < 18) ? (k + 2) : 0;
    const _Float16* nb2 = abase + (size_t)kn * 2048;
    aA0 = *(const f16x8*)(nb2);
    aA1 = *(const f16x8*)(nb2 + 512);
    aA2 = *(const f16x8*)(nb2 + 1024);
    aA3 = *(const f16x8*)(nb2 + 1536);
    K2_BODY(k + 1, aB0, aB1, aB2, aB3);
  }
#undef K2_BODY

  #pragma unroll
  for (int q = 0; q < 4; ++q) {
    float v = bv[q]; int mi = bi[q];
    #pragma unroll
    for (int off = 16; off <= 32; off <<= 1) {
      float ov = __shfl_xor(v, off, 64);
      int   oi = __shfl_xor(mi, off, 64);
      if (ov > v || (ov == v && oi < mi)) { v = ov; mi = oi; }
    }
    if (lane < 16) { wbv[wid][q * 16 + lane] = v; wbi[wid][q * 16 + lane] = mi; }
  }
  __syncthreads();

  if (t < 128) {
    int nbg = t >> 6;
    int s = t & 63;
    float v0 = wbv[nbg][s];     int i0 = wbi[nbg][s];
    float v1 = wbv[nbg + 2][s]; int i1 = wbi[nbg + 2][s];
    int mi = (v1 > v0 || (v1 == v0 && i1 < i0)) ? i1 : i0;
    idxf[t] = mi;
    int own = (tr * 4 + ((t >> 4) >> 1)) * 24 + tc * 8 + ((t & 15) >> 1);
    if (mi != own) { int o = atomicAdd(&ocnt, 1); olist[o] = t; }
  }
  __syncthreads();

  // ownership gather from xt16 (hi-only; om is f16-quantized downstream)
  for (int si = 0; si < 8; ++si) {
    const int s = wid * 8 + si;
    const int r = s >> 3, q = s & 7;
    const int m = (tr * 4 + r) * 24 + tc * 8 + q;
    const int p00 = (2 * r) * 16 + 2 * q;
    float sum = 0.f;
    int cnt = 0;
    #pragma unroll
    for (int dp = 0; dp < 4; ++dp) {
      const int p = p00 + (dp >> 1) * 16 + (dp & 1);
      if (idxf[p] == m) {
        sum += (float)th[(size_t)(p >> 4) * 6144 + (size_t)(p & 15) * 64 + lane];
        ++cnt;
      }
    }
    if (cnt > 0) {
      atomicAdd(&xsum[((size_t)bf * 576 + m) * 64 + lane], sum);
      if (lane == 0) atomicAdd(&counts[bf * 576 + m], (float)cnt);
    }
  }

  for (int o = wid; o < ocnt; o += 4) {
    const int p = olist[o];
    const int m = idxf[p];
    float v = (float)th[(size_t)(p >> 4) * 6144 + (size_t)(p & 15) * 64 + lane];
    atomicAdd(&xsum[((size_t)bf * 576 + m) * 64 + lane], v);
    if (lane == 0) atomicAdd(&counts[bf * 576 + m], 1.0f);
  }
}

// ---------------------------------------------------------------------------
// K2c: pooled GEMM + divide + GroupNorm stats:
//   om[m][co] = (W_v·xsum[m])/(cnt[m]+1) + b_v[co]   (f16 out)
// ---------------------------------------------------------------------------
__global__ __launch_bounds__(256) void k2c_pool(
    const float* __restrict__ xsum,
    const float* __restrict__ counts, const _Float16* __restrict__ w_v_h,
    const float* __restrict__ b_v, _Float16* __restrict__ om,
    float* __restrict__ gn_sum, float* __restrict__ gn_ss)
{
  const int chunk = blockIdx.x;       // 0..3
  const int bf = blockIdx.y;          // 0..63
  const int m0 = chunk * 144;
  const int t = threadIdx.x;
  const int lane = t & 63, wid = t >> 6;

  __shared__ __align__(16) _Float16 bh[144][72];
  __shared__ __align__(16) _Float16 bl[144][72];
  __shared__ float rcp_l[144];

  for (int i = t; i < 144 * 64; i += 256) {
    int mq = i >> 6, c = i & 63;
    size_t gdx = ((size_t)bf * 576 + m0 + mq) * 64 + c;
    float s = xsum[gdx];
    _Float16 hi = (_Float16)s;
    bh[mq][c] = hi;
    bl[mq][c] = (_Float16)(s - (float)hi);
  }
  if (t < 144) rcp_l[t] = 1.0f / (counts[bf * 576 + m0 + t] + 1.0f);
  __syncthreads();

  const int ccol = lane & 15, row0 = (lane >> 4) * 4, c0 = (lane >> 4) * 8;
  float sacc = 0.f, ssacc = 0.f;

  #pragma unroll
  for (int cbi = 0; cbi < 2; ++cbi) {
    const int cb = wid + cbi * 4;
    const size_t abase = (size_t)(cb * 16 + ccol) * 64;
    f16x8 a0 = *(const f16x8*)(w_v_h + abase + c0);
    f16x8 a1 = *(const f16x8*)(w_v_h + abase + 32 + c0);
    float bvv[4];
    #pragma unroll
    for (int r = 0; r < 4; ++r) bvv[r] = b_v[cb * 16 + row0 + r];
    for (int nb = 0; nb < 9; ++nb) {
      int mq = nb * 16 + ccol;
      f16x8 bh0 = *(const f16x8*)(&bh[mq][c0]);
      f16x8 bh1 = *(const f16x8*)(&bh[mq][32 + c0]);
      f16x8 bl0 = *(const f16x8*)(&bl[mq][c0]);
      f16x8 bl1 = *(const f16x8*)(&bl[mq][32 + c0]);
      f32x4 a2 = {0.f, 0.f, 0.f, 0.f};
      a2 = __builtin_amdgcn_mfma_f32_16x16x32_f16(a0, bh0, a2, 0, 0, 0);
      a2 = __builtin_amdgcn_mfma_f32_16x16x32_f16(a1, bh1, a2, 0, 0, 0);
      a2 = __builtin_amdgcn_mfma_f32_16x16x32_f16(a0, bl0, a2, 0, 0, 0);
      a2 = __builtin_amdgcn_mfma_f32_16x16x32_f16(a1, bl1, a2, 0, 0, 0);
      float rcp = rcp_l[mq];
      f16x4 o4;
      #pragma unroll
      for (int r = 0; r < 4; ++r) {
        float ov = a2[r] * rcp + bvv[r];
        sacc += ov; ssacc += ov * ov;
        o4[r] = (_Float16)ov;
      }
      *(f16x4*)(om + ((size_t)bf * 576 + m0 + mq) * 128 + cb * 16 + row0) = o4;
    }
  }

  #pragma unroll
  for (int off = 1; off < 64; off <<= 1) {
    sacc += __shfl_xor(sacc, off, 64);
    ssacc += __shfl_xor(ssacc, off, 64);
  }
  __shared__ float rs[4], rss[4];
  if (lane == 0) { rs[wid] = sacc; rss[wid] = ssacc; }
  __syncthreads();
  if (t == 0) {
    atomicAdd(gn_sum + (bf >> 2), rs[0] + rs[1] + rs[2] + rs[3]);
    atomicAdd(gn_ss + (bf >> 2), rss[0] + rss[1] + rss[2] + rss[3]);
  }
}

// ---------------------------------------------------------------------------
// K4: per (b, output row o2): skip conv as implicit GEMM, A from
//   fragment-major wsf, B from xt16 staged in LDS with XOR chunk-swizzle;
//   epilogue: GroupNorm apply + unfold + bias + add.
// ---------------------------------------------------------------------------
__global__ __launch_bounds__(256, 4) void k4_final(
    const _Float16* __restrict__ xt16, const _Float16* __restrict__ wsf,
    const float* __restrict__ b_skip, const _Float16* __restrict__ om,
    const float* __restrict__ gn_sum, const float* __restrict__ gn_ss,
    const float* __restrict__ gamma, const float* __restrict__ beta,
    float* __restrict__ out)
{
  const int o2 = blockIdx.x;          // 0..47
  const int b  = blockIdx.y;          // 0..15
  const int t = threadIdx.x;
  const int lane = t & 63, wid = t >> 6;

  __shared__ __align__(16) _Float16 xl[3 * 97 * 64];

  if (t < 96) {
    int rr = t >> 5, h2 = t & 31;
    *(unsigned int*)&xl[(rr * 97) * 64 + h2 * 2] = 0u;
  }
  for (int i = t; i < 2304; i += 256) {
    int rr = i / 768, rem = i % 768, col = rem >> 3, cg = rem & 7;
    int gr = 2 * o2 - 1 + rr;
    f16x8 v = {};
    if (gr >= 0)
      v = *(const f16x8*)(xt16 + (((size_t)b * 96 + gr) * 96 + col) * 64 + cg * 8);
    int colp = col + 1;
    *(f16x8*)&xl[(rr * 97 + colp) * 64 + ((cg ^ (colp & 7)) << 3)] = v;
  }
  __syncthreads();

  const int ccol = lane & 15, g = lane >> 4;
  const int mb0 = wid * 2;

  f32x4 acc[2][3] = {};
  const int o3a = ccol;

  #pragma unroll 1
  for (int kc = 0; kc < 6; ++kc) {
    f16x8 A[2][3];
    #pragma unroll
    for (int m2 = 0; m2 < 2; ++m2)
      #pragma unroll
      for (int kq = 0; kq < 3; ++kq) {
        int ks = kc * 3 + kq;
        A[m2][kq] = *(const f16x8*)(wsf + (((size_t)(mb0 + m2) * 18 + ks) * 64 + lane) * 8);
      }
    #pragma unroll
    for (int nb = 0; nb < 3; ++nb) {
      const int o3 = nb * 16 + o3a;
      f16x8 Bf[3];
      #pragma unroll
      for (int kq = 0; kq < 3; ++kq) {
        int ks = kc * 3 + kq;
        int dd = ks >> 1, dh = dd / 3, dw = dd % 3, ch = ks & 1;
        int colp = 2 * o3 + dw;
        Bf[kq] = *(const f16x8*)&xl[(dh * 97 + colp) * 64
                                    + ((((ch << 2) | g) ^ (colp & 7)) << 3)];
      }
      #pragma unroll
      for (int kq = 0; kq < 3; ++kq) {
        acc[0][nb] = __builtin_amdgcn_mfma_f32_16x16x32_f16(A[0][kq], Bf[kq], acc[0][nb], 0, 0, 0);
        acc[1][nb] = __builtin_amdgcn_mfma_f32_16x16x32_f16(A[1][kq], Bf[kq], acc[1][nb], 0, 0, 0);
      }
    }
  }

  const float Ninv = 1.0f / 294912.0f;
  const float mu = gn_sum[b] * Ninv;
  const float var = gn_ss[b] * Ninv - mu * mu;
  const float istd = rsqrtf(var + 1e-5f);
  const int f1 = o2 / 24, w24 = o2 % 24;

  #pragma unroll
  for (int m2 = 0; m2 < 2; ++m2) {
    const int mb = mb0 + m2;
    #pragma unroll
    for (int nb = 0; nb < 3; ++nb) {
      const int o3 = nb * 16 + o3a;
      const int f2 = o3 / 24, h = o3 % 24;
      const int bf = b * 4 + f1 * 2 + f2;
      const int m = w24 * 24 + h;
      f16x4 o4 = *(const f16x4*)(om + ((size_t)bf * 576 + m) * 128 + mb * 16 + g * 4);
      #pragma unroll
      for (int r = 0; r < 4; ++r) {
        int co = mb * 16 + g * 4 + r;
        float gnv = ((float)o4[r] - mu) * istd * gamma[co] + beta[co];
        out[((size_t)(b * 128 + co) * 48 + o2) * 48 + o3] = acc[m2][nb][r] + b_skip[co] + gnv;
      }
    }
  }
}

// ---------------------------------------------------------------------------
extern "C" void kernel_launch(void* const* d_in, const int* in_sizes, int n_in,
                              void* d_out, int out_size, void* d_ws, size_t ws_size,
                              hipStream_t stream) {
  const float* x      = (const float*)d_in[0];
  const float* w_f    = (const float*)d_in[1];
  const float* b_f    = (const float*)d_in[2];
  const float* w_v    = (const float*)d_in[3];
  const float* b_v    = (const float*)d_in[4];
  const float* w_skip = (const float*)d_in[5];
  const float* b_skip = (const float*)d_in[6];
  const float* gamma  = (const float*)d_in[7];
  const float* beta   = (const float*)d_in[8];
  float* out = (float*)d_out;

  char* ws = (char*)d_ws;
  _Float16* cenW   = (_Float16*)(ws);                 // 9,437,184 (frag-major hi+lo)
  _Float16* om     = (_Float16*)(ws);                 // aliases cenW (dead after K2)
  float*    dvec   = (float*)(ws + 9437184);          // 147,456
  _Float16* wsf    = (_Float16*)(ws + 9584640);       // 147,456
  _Float16* w_v_h  = (_Float16*)(ws + 9732096);       // 16,384
  float*    xsum   = (float*)(ws + 9748480);          // 9,437,184 (init by K1a)
  float*    counts = (float*)(ws + 19185664);         // 147,456   [memset]
  float*    gn_sum = (float*)(ws + 19333120);         // 256       [memset]
  float*    gn_ss  = (float*)(ws + 19333376);         // 256       [memset]
  _Float16* xt16   = (_Float16*)(ws + 19333632);      // 18,874,368
  _Float16* wfA    = (_Float16*)(ws + 38208000);      // 32,768
  _Float16* wfT    = (_Float16*)(ws + 38240768);      // 32,768
  _Float16* xlo16  = (_Float16*)(ws + 38273536);      // 18,874,368 (end 57,147,904)

  hipMemsetAsync(ws + 19185664, 0, 147968, stream);

  k1a_prep<<<dim3(784), dim3(256), 0, stream>>>(
      x, w_f, w_v, w_skip, xt16, xlo16, xsum, wfA, wfT, w_v_h, wsf);
  k1b_centers<<<dim3(6, 64), dim3(256), 0, stream>>>(
      xsum, b_f, wfA, wfT, cenW, dvec);
  k2_assign<<<dim3(1152), dim3(256), 0, stream>>>(
      xt16, xlo16, cenW, dvec, xsum, counts);
  k2c_pool<<<dim3(4, 64), dim3(256), 0, stream>>>(
      xsum, counts, w_v_h, b_v, om, gn_sum, gn_ss);
  k4_final<<<dim3(48, 16), dim3(256), 0, stream>>>(
      xt16, wsf, b_skip, om, gn_sum, gn_ss, gamma, beta, out);
}

// Round 14
// 120.283 us; speedup vs baseline: 1.0647x; 1.0647x over previous
//
#include <hip/hip_runtime.h>

typedef _Float16 f16x8 __attribute__((ext_vector_type(8)));
typedef _Float16 f16x4 __attribute__((ext_vector_type(4)));
typedef float f32x4 __attribute__((ext_vector_type(4)));

// ---------------------------------------------------------------------------
// K1a: blocks 0..767 (b x row-pair): transpose x -> xt16 (f16 hi) AND
//      xlo16 (f16 residual), write 2x2 avgpool (exact f32) into xsum.
//      blocks 768..783: weight prep (wfA/wfT/w_v_h/wsf).
// ---------------------------------------------------------------------------
__global__ __launch_bounds__(256) void k1a_prep(
    const float* __restrict__ x, const float* __restrict__ w_f,
    const float* __restrict__ w_v, const float* __restrict__ w_skip,
    _Float16* __restrict__ xt16, _Float16* __restrict__ xlo16,
    float* __restrict__ xsum,
    _Float16* __restrict__ wfA, _Float16* __restrict__ wfT,
    _Float16* __restrict__ w_v_h, _Float16* __restrict__ wsf)
{
  const int bid = blockIdx.x;
  const int t = threadIdx.x;

  if (bid >= 768) {
    const int wb = bid - 768;         // 0..15
    for (int i = wb * 512 + t; i < wb * 512 + 512; i += 256) {
      int co = i >> 6, c = i & 63;
      float w = w_f[i];
      _Float16 hi = (_Float16)w, lo = (_Float16)(w - (float)hi);
      int laneA = (co & 15) | (((c >> 3) & 3) << 4);
      int jA = c >> 5;
      size_t oA = ((size_t)(co >> 4) * 4) * 512 + (size_t)laneA * 8 + (c & 7);
      wfA[oA + (size_t)jA * 512] = hi;
      wfA[oA + (size_t)(jA + 2) * 512] = lo;
      int laneT = (c & 15) | (((co >> 3) & 3) << 4);
      int jT = co >> 5;
      size_t oT = ((size_t)(c >> 4) * 8) * 512 + (size_t)laneT * 8 + (co & 7);
      wfT[oT + (size_t)jT * 512] = hi;
      wfT[oT + (size_t)(jT + 4) * 512] = lo;
    }
    for (int i = wb * 512 + t; i < wb * 512 + 512; i += 256)
      w_v_h[i] = (_Float16)w_v[i];
    for (int i = wb * 4608 + t; i < wb * 4608 + 4608; i += 256) {
      int co = i / 576, kk = i % 576;
      int dd = kk >> 6, c = kk & 63, dh = dd / 3, dw = dd % 3;
      int mb = co >> 4, ccol = co & 15;
      int ks = kk >> 5, g = (kk >> 3) & 3, e = kk & 7;
      size_t dst = (((size_t)mb * 18 + ks) * 64 + (ccol | (g << 4))) * 8 + e;
      wsf[dst] = (_Float16)w_skip[((co * 64 + c) * 3 + dh) * 3 + dw];
    }
    return;
  }

  const int b = bid / 48, rp = bid % 48;
  const int c = t >> 2, q = t & 3;
  __shared__ __align__(16) _Float16 xst[2 * 96 * 72];   // pitch 72 = 144 B
  __shared__ __align__(16) _Float16 xsl[2 * 96 * 72];

  float pool[12];
  #pragma unroll
  for (int p = 0; p < 12; ++p) pool[p] = 0.f;

  #pragma unroll
  for (int r = 0; r < 2; ++r) {
    const float* xr = x + ((size_t)(b * 64 + c) * 96 + 2 * rp + r) * 96 + q * 24;
    #pragma unroll
    for (int j2 = 0; j2 < 6; ++j2) {
      f32x4 v = *(const f32x4*)(xr + j2 * 4);
      #pragma unroll
      for (int u = 0; u < 4; ++u) {
        int C = q * 24 + j2 * 4 + u;
        _Float16 hi = (_Float16)v[u];
        xst[(r * 96 + C) * 72 + c] = hi;
        xsl[(r * 96 + C) * 72 + c] = (_Float16)(v[u] - (float)hi);
        pool[(j2 * 4 + u) >> 1] += v[u];
      }
    }
  }
  {
    const int f1 = rp >= 24 ? 1 : 0, wl = rp - f1 * 24;
    #pragma unroll
    for (int p = 0; p < 12; ++p) {
      int C = q * 24 + 2 * p;
      int f2 = C >= 48 ? 1 : 0;
      int m = wl * 24 + (C - f2 * 48) / 2;
      xsum[((size_t)(b * 4 + f1 * 2 + f2) * 576 + m) * 64 + c] = 0.25f * pool[p];
    }
  }
  __syncthreads();
  for (int i = t; i < 1536; i += 256) {
    int r = i / 768, rem = i % 768, col = rem >> 3, cg = rem & 7;
    size_t gdst = (((size_t)b * 96 + 2 * rp + r) * 96 + col) * 64 + cg * 8;
    *(f16x8*)(xt16 + gdst) = *(const f16x8*)&xst[(r * 96 + col) * 72 + cg * 8];
    *(f16x8*)(xlo16 + gdst) = *(const f16x8*)&xsl[(r * 96 + col) * 72 + cg * 8];
  }
}

// ---------------------------------------------------------------------------
// K1b: per (m-chunk of 96, bf): centers via MFMA (3-term hi/lo split),
//   in-register norm reduce, cenW written in K2's fragment-major layout.
// ---------------------------------------------------------------------------
__global__ __launch_bounds__(256) void k1b_centers(
    const float* __restrict__ xsum, const float* __restrict__ b_f,
    const _Float16* __restrict__ wfA, const _Float16* __restrict__ wfT,
    _Float16* __restrict__ cenW, float* __restrict__ dvec)
{
  const int mc = blockIdx.x;          // 0..5
  const int bf = blockIdx.y;          // 0..63
  const int m0 = mc * 96;
  const int t = threadIdx.x;
  const int lane = t & 63, wid = t >> 6;
  const int ccol = lane & 15, g = lane >> 4;

  __shared__ __align__(16) _Float16 cenT_h[96][136];
  __shared__ __align__(16) _Float16 cenT_l[96][136];
  __shared__ __align__(16) _Float16 xcs_h[96][72];
  __shared__ __align__(16) _Float16 xcs_l[96][72];
  float* part = (float*)&xcs_h[0][0];   // aliased after GEMM1 (sync-guarded)

  for (int i = t; i < 96 * 64; i += 256) {
    int m = i >> 6, c = i & 63;
    float s = xsum[((size_t)bf * 576 + m0 + m) * 64 + c];
    _Float16 hi = (_Float16)s;
    xcs_h[m][c] = hi;
    xcs_l[m][c] = (_Float16)(s - (float)hi);
  }
  __syncthreads();

  f32x4 acc[2][6];
  f32x4 bfv[2];
  #pragma unroll
  for (int cbi = 0; cbi < 2; ++cbi) {
    const int cb = wid + cbi * 4;
    bfv[cbi] = *(const f32x4*)(b_f + cb * 16 + g * 4);
    const _Float16* wa = wfA + (size_t)cb * 2048 + (size_t)lane * 8;
    f16x8 a0h = *(const f16x8*)(wa);
    f16x8 a1h = *(const f16x8*)(wa + 512);
    f16x8 a0l = *(const f16x8*)(wa + 1024);
    f16x8 a1l = *(const f16x8*)(wa + 1536);
    #pragma unroll
    for (int nb = 0; nb < 6; ++nb) {
      const int m = nb * 16 + ccol;
      f16x8 b0h = *(const f16x8*)&xcs_h[m][g * 8];
      f16x8 b1h = *(const f16x8*)&xcs_h[m][32 + g * 8];
      f16x8 b0l = *(const f16x8*)&xcs_l[m][g * 8];
      f16x8 b1l = *(const f16x8*)&xcs_l[m][32 + g * 8];
      f32x4 a2 = bfv[cbi];
      a2 = __builtin_amdgcn_mfma_f32_16x16x32_f16(a0h, b0h, a2, 0, 0, 0);
      a2 = __builtin_amdgcn_mfma_f32_16x16x32_f16(a1h, b1h, a2, 0, 0, 0);
      a2 = __builtin_amdgcn_mfma_f32_16x16x32_f16(a0h, b0l, a2, 0, 0, 0);
      a2 = __builtin_amdgcn_mfma_f32_16x16x32_f16(a1h, b1l, a2, 0, 0, 0);
      a2 = __builtin_amdgcn_mfma_f32_16x16x32_f16(a0l, b0h, a2, 0, 0, 0);
      a2 = __builtin_amdgcn_mfma_f32_16x16x32_f16(a1l, b1h, a2, 0, 0, 0);
      acc[cbi][nb] = a2;
    }
  }
  __syncthreads();   // all xcs reads complete; part may now alias it

  #pragma unroll
  for (int nb = 0; nb < 6; ++nb) {
    float ss = 0.f, db = 0.f;
    #pragma unroll
    for (int cbi = 0; cbi < 2; ++cbi)
      #pragma unroll
      for (int r = 0; r < 4; ++r) {
        float v = acc[cbi][nb][r];
        ss = fmaf(v, v, ss);
        db = fmaf(v, bfv[cbi][r], db);
      }
    #pragma unroll
    for (int off = 16; off <= 32; off <<= 1) {
      ss += __shfl_xor(ss, off, 64);
      db += __shfl_xor(db, off, 64);
    }
    if (lane < 16) {
      part[wid * 96 + nb * 16 + lane] = ss;
      part[384 + wid * 96 + nb * 16 + lane] = db;
    }
  }
  __syncthreads();
  if (t < 96) {
    float ss = part[t] + part[96 + t] + part[192 + t] + part[288 + t];
    float db = part[384 + t] + part[480 + t] + part[576 + t] + part[672 + t];
    float inv = 1.0f / fmaxf(sqrtf(ss), 1e-12f);
    part[768 + t] = inv;
    dvec[bf * 576 + m0 + t] = inv * db;
  }
  __syncthreads();

  #pragma unroll
  for (int nb = 0; nb < 6; ++nb) {
    const int m = nb * 16 + ccol;
    const float inv = part[768 + m];
    #pragma unroll
    for (int cbi = 0; cbi < 2; ++cbi) {
      const int cb = wid + cbi * 4;
      #pragma unroll
      for (int r = 0; r < 4; ++r) {
        float v = acc[cbi][nb][r] * inv;
        _Float16 hi = (_Float16)v;
        cenT_h[m][cb * 16 + g * 4 + r] = hi;
        cenT_l[m][cb * 16 + g * 4 + r] = (_Float16)(v - (float)hi);
      }
    }
  }
  __syncthreads();

  // GEMM2: wave wid owns c-block wid; B = wfT frags (global, coalesced)
  const _Float16* wt = wfT + (size_t)wid * 4096 + (size_t)lane * 8;
  f16x8 tbh[4], tbl[4];
  #pragma unroll
  for (int j2 = 0; j2 < 4; ++j2) {
    tbh[j2] = *(const f16x8*)(wt + j2 * 512);
    tbl[j2] = *(const f16x8*)(wt + (j2 + 4) * 512);
  }
  #pragma unroll 1
  for (int mb = 0; mb < 6; ++mb) {
    f16x8 tah[4], tal[4];
    #pragma unroll
    for (int j2 = 0; j2 < 4; ++j2) {
      tah[j2] = *(const f16x8*)&cenT_h[mb * 16 + ccol][j2 * 32 + g * 8];
      tal[j2] = *(const f16x8*)&cenT_l[mb * 16 + ccol][j2 * 32 + g * 8];
    }
    f32x4 a2 = {0.f, 0.f, 0.f, 0.f};
    #pragma unroll
    for (int j2 = 0; j2 < 4; ++j2) {
      a2 = __builtin_amdgcn_mfma_f32_16x16x32_f16(tah[j2], tbh[j2], a2, 0, 0, 0);
      a2 = __builtin_amdgcn_mfma_f32_16x16x32_f16(tah[j2], tbl[j2], a2, 0, 0, 0);
      a2 = __builtin_amdgcn_mfma_f32_16x16x32_f16(tal[j2], tbh[j2], a2, 0, 0, 0);
    }
    const int c = wid * 16 + ccol;
    const int lane2g = ((c >> 3) & 3) << 4;
    const int j2f = c >> 5, e = c & 7;
    #pragma unroll
    for (int r = 0; r < 4; ++r) {
      float v = a2[r];
      _Float16 hi = (_Float16)v;
      _Float16 lo = (_Float16)(v - (float)hi);
      size_t base = (((size_t)bf * 36 + mc * 6 + mb) * 4) * 512
                  + (size_t)((g * 4 + r) | lane2g) * 8 + e;
      cenW[base + (size_t)j2f * 512] = hi;
      cenW[base + (size_t)(j2f + 2) * 512] = lo;
    }
  }
}

// ---------------------------------------------------------------------------
// K2: per (bf, tile of 128 points): argmax via 3-term split f16 MFMA.
//   HYBRID staging (r12 gather speed + r13 split elimination):
//   - xh[128][72] f16 hi staged coalesced from xt16 (no cvt/sub VALU);
//   - B-lo fragments direct from xlo16 global (8 loads/wave, one-time);
//   - B-hi + ownership gather from LDS xh (hi-only gather: 5e-4 rel err,
//     validated r13, om is f16-quantized downstream).
//   LDS ~23 KB. Main loop/merge/gather logic byte-identical to r12 (argmax
//   bit-identical). Chain-accumulate MFMA, strict-> argmax, 2-deep ping-pong.
// ---------------------------------------------------------------------------
__global__ __launch_bounds__(256, 4) void k2_assign(
    const _Float16* __restrict__ xt16, const _Float16* __restrict__ xlo16,
    const _Float16* __restrict__ cenW,
    const float* __restrict__ dvec,
    float* __restrict__ xsum, float* __restrict__ counts)
{
  const int id = blockIdx.x;          // 0..1151
  const int xcd = id & 7;
  const int j = id >> 3;              // 0..143
  const int bf = xcd * 8 + j / 18;
  const int tile = j % 18;
  const int b = bf >> 2, f1 = (bf >> 1) & 1, f2 = bf & 1;
  const int t = threadIdx.x;
  const int lane = t & 63, wid = t >> 6;

  const int tr = tile / 3, tc = tile % 3;
  const int w0 = tr * 8, h0 = tc * 16;

  __shared__ __align__(16) _Float16 xh[128][72];
  __shared__ __align__(16) float dvl[576];
  __shared__ float wbv[4][64];
  __shared__ int   wbi[4][64];
  __shared__ int   idxf[128];
  __shared__ int   olist[128];
  __shared__ int   ocnt;

  if (t == 0) ocnt = 0;
  for (int i = t; i < 576; i += 256) dvl[i] = dvec[bf * 576 + i];

  // tile base in xt16/xlo16: [b][R][C][c]; point p = row*16+col maps to
  // global (row*6144 + col*64), row = p>>4, col = p&15
  const size_t tbase = (((size_t)b * 96 + f1 * 48 + w0) * 96 + f2 * 48 + h0) * 64;

  // stage hi tile: 1024 f16x8 chunks, coalesced
  for (int i = t; i < 1024; i += 256) {
    int jj = i >> 3, cg = i & 7;
    f16x8 v = *(const f16x8*)(xt16 + tbase
                + ((size_t)(jj >> 4) * 96 + (jj & 15)) * 64 + cg * 8);
    *(f16x8*)&xh[jj][cg * 8] = v;
  }

  const int ccol = lane & 15;
  const int g = lane >> 4;
  const int half = wid >> 1;          // mb half (0: 0..17, 1: 18..35)
  const int nbh = wid & 1;            // n-block half (0: n<64, 1: n>=64)

  // B-lo fragments direct from global (one contiguous 2KB row per n-block)
  f16x8 Bl0[4], Bl1[4];
  #pragma unroll
  for (int q = 0; q < 4; ++q) {
    const size_t po = tbase + (size_t)(nbh * 4 + q) * 6144 + (size_t)ccol * 64 + g * 8;
    Bl0[q] = *(const f16x8*)(xlo16 + po);
    Bl1[q] = *(const f16x8*)(xlo16 + po + 32);
  }
  __syncthreads();

  // B-hi fragments from LDS
  f16x8 Bh0[4], Bh1[4];
  #pragma unroll
  for (int q = 0; q < 4; ++q) {
    const int p = (nbh * 4 + q) * 16 + ccol;
    Bh0[q] = *(const f16x8*)&xh[p][g * 8];
    Bh1[q] = *(const f16x8*)&xh[p][32 + g * 8];
  }

  const int mb0 = half * 18;
  const _Float16* abase = cenW + (size_t)bf * 73728 + (size_t)mb0 * 2048
                        + (size_t)lane * 8;

  float bv[4];
  int bi[4];
  #pragma unroll
  for (int q = 0; q < 4; ++q) { bv[q] = -3.0e38f; bi[q] = 0; }

  f16x8 aA0 = *(const f16x8*)(abase);
  f16x8 aA1 = *(const f16x8*)(abase + 512);
  f16x8 aA2 = *(const f16x8*)(abase + 1024);
  f16x8 aA3 = *(const f16x8*)(abase + 1536);
  f16x8 aB0, aB1, aB2, aB3;

#define K2_BODY(kk, A0, A1, A2, A3)                                          \
  {                                                                          \
    const int mb = mb0 + (kk);                                               \
    f32x4 dv4 = *(const f32x4*)&dvl[mb * 16 + g * 4];                        \
    _Pragma("unroll")                                                        \
    for (int q = 0; q < 4; ++q) {                                            \
      f32x4 a4 = dv4;                                                        \
      a4 = __builtin_amdgcn_mfma_f32_16x16x32_f16(A0, Bh0[q], a4, 0, 0, 0);  \
      a4 = __builtin_amdgcn_mfma_f32_16x16x32_f16(A1, Bh1[q], a4, 0, 0, 0);  \
      a4 = __builtin_amdgcn_mfma_f32_16x16x32_f16(A0, Bl0[q], a4, 0, 0, 0);  \
      a4 = __builtin_amdgcn_mfma_f32_16x16x32_f16(A1, Bl1[q], a4, 0, 0, 0);  \
      a4 = __builtin_amdgcn_mfma_f32_16x16x32_f16(A2, Bh0[q], a4, 0, 0, 0);  \
      a4 = __builtin_amdgcn_mfma_f32_16x16x32_f16(A3, Bh1[q], a4, 0, 0, 0);  \
      _Pragma("unroll")                                                      \
      for (int r = 0; r < 4; ++r) {                                          \
        float vv = a4[r];                                                    \
        if (vv > bv[q]) { bv[q] = vv; bi[q] = mb * 16 + g * 4 + r; }         \
      }                                                                      \
    }                                                                        \
  }

  #pragma unroll 1
  for (int k = 0; k < 18; k += 2) {
    const _Float16* nb1 = abase + (size_t)(k + 1) * 2048;
    aB0 = *(const f16x8*)(nb1);
    aB1 = *(const f16x8*)(nb1 + 512);
    aB2 = *(const f16x8*)(nb1 + 1024);
    aB3 = *(const f16x8*)(nb1 + 1536);
    K2_BODY(k, aA0, aA1, aA2, aA3);
    const int kn = (k + 2 < 18) ? (k + 2) : 0;
    const _Float16* nb2 = abase + (size_t)kn * 2048;
    aA0 = *(const f16x8*)(nb2);
    aA1 = *(const f16x8*)(nb2 + 512);
    aA2 = *(const f16x8*)(nb2 + 1024);
    aA3 = *(const f16x8*)(nb2 + 1536);
    K2_BODY(k + 1, aB0, aB1, aB2, aB3);
  }
#undef K2_BODY

  #pragma unroll
  for (int q = 0; q < 4; ++q) {
    float v = bv[q]; int mi = bi[q];
    #pragma unroll
    for (int off = 16; off <= 32; off <<= 1) {
      float ov = __shfl_xor(v, off, 64);
      int   oi = __shfl_xor(mi, off, 64);
      if (ov > v || (ov == v && oi < mi)) { v = ov; mi = oi; }
    }
    if (lane < 16) { wbv[wid][q * 16 + lane] = v; wbi[wid][q * 16 + lane] = mi; }
  }
  __syncthreads();

  if (t < 128) {
    int nbg = t >> 6;
    int s = t & 63;
    float v0 = wbv[nbg][s];     int i0 = wbi[nbg][s];
    float v1 = wbv[nbg + 2][s]; int i1 = wbi[nbg + 2][s];
    int mi = (v1 > v0 || (v1 == v0 && i1 < i0)) ? i1 : i0;
    idxf[t] = mi;
    int own = (tr * 4 + ((t >> 4) >> 1)) * 24 + tc * 8 + ((t & 15) >> 1);
    if (mi != own) { int o = atomicAdd(&ocnt, 1); olist[o] = t; }
  }
  __syncthreads();

  // ownership gather from LDS xh (hi-only; om is f16-quantized downstream)
  for (int si = 0; si < 8; ++si) {
    const int s = wid * 8 + si;
    const int r = s >> 3, q = s & 7;
    const int m = (tr * 4 + r) * 24 + tc * 8 + q;
    const int p00 = (2 * r) * 16 + 2 * q;
    float sum = 0.f;
    int cnt = 0;
    #pragma unroll
    for (int dp = 0; dp < 4; ++dp) {
      const int p = p00 + (dp >> 1) * 16 + (dp & 1);
      if (idxf[p] == m) { sum += (float)xh[p][lane]; ++cnt; }
    }
    if (cnt > 0) {
      atomicAdd(&xsum[((size_t)bf * 576 + m) * 64 + lane], sum);
      if (lane == 0) atomicAdd(&counts[bf * 576 + m], (float)cnt);
    }
  }

  for (int o = wid; o < ocnt; o += 4) {
    const int p = olist[o];
    const int m = idxf[p];
    atomicAdd(&xsum[((size_t)bf * 576 + m) * 64 + lane], (float)xh[p][lane]);
    if (lane == 0) atomicAdd(&counts[bf * 576 + m], 1.0f);
  }
}

// ---------------------------------------------------------------------------
// K2c: pooled GEMM + divide + GroupNorm stats:
//   om[m][co] = (W_v·xsum[m])/(cnt[m]+1) + b_v[co]   (f16 out)
// ---------------------------------------------------------------------------
__global__ __launch_bounds__(256) void k2c_pool(
    const float* __restrict__ xsum,
    const float* __restrict__ counts, const _Float16* __restrict__ w_v_h,
    const float* __restrict__ b_v, _Float16* __restrict__ om,
    float* __restrict__ gn_sum, float* __restrict__ gn_ss)
{
  const int chunk = blockIdx.x;       // 0..3
  const int bf = blockIdx.y;          // 0..63
  const int m0 = chunk * 144;
  const int t = threadIdx.x;
  const int lane = t & 63, wid = t >> 6;

  __shared__ __align__(16) _Float16 bh[144][72];
  __shared__ __align__(16) _Float16 bl[144][72];
  __shared__ float rcp_l[144];

  for (int i = t; i < 144 * 64; i += 256) {
    int mq = i >> 6, c = i & 63;
    size_t gdx = ((size_t)bf * 576 + m0 + mq) * 64 + c;
    float s = xsum[gdx];
    _Float16 hi = (_Float16)s;
    bh[mq][c] = hi;
    bl[mq][c] = (_Float16)(s - (float)hi);
  }
  if (t < 144) rcp_l[t] = 1.0f / (counts[bf * 576 + m0 + t] + 1.0f);
  __syncthreads();

  const int ccol = lane & 15, row0 = (lane >> 4) * 4, c0 = (lane >> 4) * 8;
  float sacc = 0.f, ssacc = 0.f;

  #pragma unroll
  for (int cbi = 0; cbi < 2; ++cbi) {
    const int cb = wid + cbi * 4;
    const size_t abase = (size_t)(cb * 16 + ccol) * 64;
    f16x8 a0 = *(const f16x8*)(w_v_h + abase + c0);
    f16x8 a1 = *(const f16x8*)(w_v_h + abase + 32 + c0);
    float bvv[4];
    #pragma unroll
    for (int r = 0; r < 4; ++r) bvv[r] = b_v[cb * 16 + row0 + r];
    for (int nb = 0; nb < 9; ++nb) {
      int mq = nb * 16 + ccol;
      f16x8 bh0 = *(const f16x8*)(&bh[mq][c0]);
      f16x8 bh1 = *(const f16x8*)(&bh[mq][32 + c0]);
      f16x8 bl0 = *(const f16x8*)(&bl[mq][c0]);
      f16x8 bl1 = *(const f16x8*)(&bl[mq][32 + c0]);
      f32x4 a2 = {0.f, 0.f, 0.f, 0.f};
      a2 = __builtin_amdgcn_mfma_f32_16x16x32_f16(a0, bh0, a2, 0, 0, 0);
      a2 = __builtin_amdgcn_mfma_f32_16x16x32_f16(a1, bh1, a2, 0, 0, 0);
      a2 = __builtin_amdgcn_mfma_f32_16x16x32_f16(a0, bl0, a2, 0, 0, 0);
      a2 = __builtin_amdgcn_mfma_f32_16x16x32_f16(a1, bl1, a2, 0, 0, 0);
      float rcp = rcp_l[mq];
      f16x4 o4;
      #pragma unroll
      for (int r = 0; r < 4; ++r) {
        float ov = a2[r] * rcp + bvv[r];
        sacc += ov; ssacc += ov * ov;
        o4[r] = (_Float16)ov;
      }
      *(f16x4*)(om + ((size_t)bf * 576 + m0 + mq) * 128 + cb * 16 + row0) = o4;
    }
  }

  #pragma unroll
  for (int off = 1; off < 64; off <<= 1) {
    sacc += __shfl_xor(sacc, off, 64);
    ssacc += __shfl_xor(ssacc, off, 64);
  }
  __shared__ float rs[4], rss[4];
  if (lane == 0) { rs[wid] = sacc; rss[wid] = ssacc; }
  __syncthreads();
  if (t == 0) {
    atomicAdd(gn_sum + (bf >> 2), rs[0] + rs[1] + rs[2] + rs[3]);
    atomicAdd(gn_ss + (bf >> 2), rss[0] + rss[1] + rss[2] + rss[3]);
  }
}

// ---------------------------------------------------------------------------
// K4: per (b, output row o2): skip conv as implicit GEMM, A from
//   fragment-major wsf, B from xt16 staged in LDS with XOR chunk-swizzle;
//   epilogue: GroupNorm apply + unfold + bias + add.
// ---------------------------------------------------------------------------
__global__ __launch_bounds__(256, 4) void k4_final(
    const _Float16* __restrict__ xt16, const _Float16* __restrict__ wsf,
    const float* __restrict__ b_skip, const _Float16* __restrict__ om,
    const float* __restrict__ gn_sum, const float* __restrict__ gn_ss,
    const float* __restrict__ gamma, const float* __restrict__ beta,
    float* __restrict__ out)
{
  const int o2 = blockIdx.x;          // 0..47
  const int b  = blockIdx.y;          // 0..15
  const int t = threadIdx.x;
  const int lane = t & 63, wid = t >> 6;

  __shared__ __align__(16) _Float16 xl[3 * 97 * 64];

  if (t < 96) {
    int rr = t >> 5, h2 = t & 31;
    *(unsigned int*)&xl[(rr * 97) * 64 + h2 * 2] = 0u;
  }
  for (int i = t; i < 2304; i += 256) {
    int rr = i / 768, rem = i % 768, col = rem >> 3, cg = rem & 7;
    int gr = 2 * o2 - 1 + rr;
    f16x8 v = {};
    if (gr >= 0)
      v = *(const f16x8*)(xt16 + (((size_t)b * 96 + gr) * 96 + col) * 64 + cg * 8);
    int colp = col + 1;
    *(f16x8*)&xl[(rr * 97 + colp) * 64 + ((cg ^ (colp & 7)) << 3)] = v;
  }
  __syncthreads();

  const int ccol = lane & 15, g = lane >> 4;
  const int mb0 = wid * 2;

  f32x4 acc[2][3] = {};
  const int o3a = ccol;

  #pragma unroll 1
  for (int kc = 0; kc < 6; ++kc) {
    f16x8 A[2][3];
    #pragma unroll
    for (int m2 = 0; m2 < 2; ++m2)
      #pragma unroll
      for (int kq = 0; kq < 3; ++kq) {
        int ks = kc * 3 + kq;
        A[m2][kq] = *(const f16x8*)(wsf + (((size_t)(mb0 + m2) * 18 + ks) * 64 + lane) * 8);
      }
    #pragma unroll
    for (int nb = 0; nb < 3; ++nb) {
      const int o3 = nb * 16 + o3a;
      f16x8 Bf[3];
      #pragma unroll
      for (int kq = 0; kq < 3; ++kq) {
        int ks = kc * 3 + kq;
        int dd = ks >> 1, dh = dd / 3, dw = dd % 3, ch = ks & 1;
        int colp = 2 * o3 + dw;
        Bf[kq] = *(const f16x8*)&xl[(dh * 97 + colp) * 64
                                    + ((((ch << 2) | g) ^ (colp & 7)) << 3)];
      }
      #pragma unroll
      for (int kq = 0; kq < 3; ++kq) {
        acc[0][nb] = __builtin_amdgcn_mfma_f32_16x16x32_f16(A[0][kq], Bf[kq], acc[0][nb], 0, 0, 0);
        acc[1][nb] = __builtin_amdgcn_mfma_f32_16x16x32_f16(A[1][kq], Bf[kq], acc[1][nb], 0, 0, 0);
      }
    }
  }

  const float Ninv = 1.0f / 294912.0f;
  const float mu = gn_sum[b] * Ninv;
  const float var = gn_ss[b] * Ninv - mu * mu;
  const float istd = rsqrtf(var + 1e-5f);
  const int f1 = o2 / 24, w24 = o2 % 24;

  #pragma unroll
  for (int m2 = 0; m2 < 2; ++m2) {
    const int mb = mb0 + m2;
    #pragma unroll
    for (int nb = 0; nb < 3; ++nb) {
      const int o3 = nb * 16 + o3a;
      const int f2 = o3 / 24, h = o3 % 24;
      const int bf = b * 4 + f1 * 2 + f2;
      const int m = w24 * 24 + h;
      f16x4 o4 = *(const f16x4*)(om + ((size_t)bf * 576 + m) * 128 + mb * 16 + g * 4);
      #pragma unroll
      for (int r = 0; r < 4; ++r) {
        int co = mb * 16 + g * 4 + r;
        float gnv = ((float)o4[r] - mu) * istd * gamma[co] + beta[co];
        out[((size_t)(b * 128 + co) * 48 + o2) * 48 + o3] = acc[m2][nb][r] + b_skip[co] + gnv;
      }
    }
  }
}

// ---------------------------------------------------------------------------
extern "C" void kernel_launch(void* const* d_in, const int* in_sizes, int n_in,
                              void* d_out, int out_size, void* d_ws, size_t ws_size,
                              hipStream_t stream) {
  const float* x      = (const float*)d_in[0];
  const float* w_f    = (const float*)d_in[1];
  const float* b_f    = (const float*)d_in[2];
  const float* w_v    = (const float*)d_in[3];
  const float* b_v    = (const float*)d_in[4];
  const float* w_skip = (const float*)d_in[5];
  const float* b_skip = (const float*)d_in[6];
  const float* gamma  = (const float*)d_in[7];
  const float* beta   = (const float*)d_in[8];
  float* out = (float*)d_out;

  char* ws = (char*)d_ws;
  _Float16* cenW   = (_Float16*)(ws);                 // 9,437,184 (frag-major hi+lo)
  _Float16* om     = (_Float16*)(ws);                 // aliases cenW (dead after K2)
  float*    dvec   = (float*)(ws + 9437184);          // 147,456
  _Float16* wsf    = (_Float16*)(ws + 9584640);       // 147,456
  _Float16* w_v_h  = (_Float16*)(ws + 9732096);       // 16,384
  float*    xsum   = (float*)(ws + 9748480);          // 9,437,184 (init by K1a)
  float*    counts = (float*)(ws + 19185664);         // 147,456   [memset]
  float*    gn_sum = (float*)(ws + 19333120);         // 256       [memset]
  float*    gn_ss  = (float*)(ws + 19333376);         // 256       [memset]
  _Float16* xt16   = (_Float16*)(ws + 19333632);      // 18,874,368
  _Float16* wfA    = (_Float16*)(ws + 38208000);      // 32,768
  _Float16* wfT    = (_Float16*)(ws + 38240768);      // 32,768
  _Float16* xlo16  = (_Float16*)(ws + 38273536);      // 18,874,368 (end 57,147,904)

  hipMemsetAsync(ws + 19185664, 0, 147968, stream);

  k1a_prep<<<dim3(784), dim3(256), 0, stream>>>(
      x, w_f, w_v, w_skip, xt16, xlo16, xsum, wfA, wfT, w_v_h, wsf);
  k1b_centers<<<dim3(6, 64), dim3(256), 0, stream>>>(
      xsum, b_f, wfA, wfT, cenW, dvec);
  k2_assign<<<dim3(1152), dim3(256), 0, stream>>>(
      xt16, xlo16, cenW, dvec, xsum, counts);
  k2c_pool<<<dim3(4, 64), dim3(256), 0, stream>>>(
      xsum, counts, w_v_h, b_v, om, gn_sum, gn_ss);
  k4_final<<<dim3(48, 16), dim3(256), 0, stream>>>(
      xt16, wsf, b_skip, om, gn_sum, gn_ss, gamma, beta, out);
}

// Round 15
// 116.033 us; speedup vs baseline: 1.1037x; 1.0366x over previous
//
#include <hip/hip_runtime.h>

typedef _Float16 f16x8 __attribute__((ext_vector_type(8)));
typedef _Float16 f16x4 __attribute__((ext_vector_type(4)));
typedef float f32x4 __attribute__((ext_vector_type(4)));

// ---------------------------------------------------------------------------
// K1a: blocks 0..767 (b x row-pair): transpose x -> xt16 (f16 hi) AND
//      xlo16 (f16 residual), write 2x2 avgpool (exact f32) into xsum.
//      blocks 768..783: weight prep (wfA/wfT/w_v_h/wsf).
// ---------------------------------------------------------------------------
__global__ __launch_bounds__(256) void k1a_prep(
    const float* __restrict__ x, const float* __restrict__ w_f,
    const float* __restrict__ w_v, const float* __restrict__ w_skip,
    _Float16* __restrict__ xt16, _Float16* __restrict__ xlo16,
    float* __restrict__ xsum,
    _Float16* __restrict__ wfA, _Float16* __restrict__ wfT,
    _Float16* __restrict__ w_v_h, _Float16* __restrict__ wsf)
{
  const int bid = blockIdx.x;
  const int t = threadIdx.x;

  if (bid >= 768) {
    const int wb = bid - 768;         // 0..15
    for (int i = wb * 512 + t; i < wb * 512 + 512; i += 256) {
      int co = i >> 6, c = i & 63;
      float w = w_f[i];
      _Float16 hi = (_Float16)w, lo = (_Float16)(w - (float)hi);
      int laneA = (co & 15) | (((c >> 3) & 3) << 4);
      int jA = c >> 5;
      size_t oA = ((size_t)(co >> 4) * 4) * 512 + (size_t)laneA * 8 + (c & 7);
      wfA[oA + (size_t)jA * 512] = hi;
      wfA[oA + (size_t)(jA + 2) * 512] = lo;
      int laneT = (c & 15) | (((co >> 3) & 3) << 4);
      int jT = co >> 5;
      size_t oT = ((size_t)(c >> 4) * 8) * 512 + (size_t)laneT * 8 + (co & 7);
      wfT[oT + (size_t)jT * 512] = hi;
      wfT[oT + (size_t)(jT + 4) * 512] = lo;
    }
    for (int i = wb * 512 + t; i < wb * 512 + 512; i += 256)
      w_v_h[i] = (_Float16)w_v[i];
    for (int i = wb * 4608 + t; i < wb * 4608 + 4608; i += 256) {
      int co = i / 576, kk = i % 576;
      int dd = kk >> 6, c = kk & 63, dh = dd / 3, dw = dd % 3;
      int mb = co >> 4, ccol = co & 15;
      int ks = kk >> 5, g = (kk >> 3) & 3, e = kk & 7;
      size_t dst = (((size_t)mb * 18 + ks) * 64 + (ccol | (g << 4))) * 8 + e;
      wsf[dst] = (_Float16)w_skip[((co * 64 + c) * 3 + dh) * 3 + dw];
    }
    return;
  }

  const int b = bid / 48, rp = bid % 48;
  const int c = t >> 2, q = t & 3;
  __shared__ __align__(16) _Float16 xst[2 * 96 * 72];   // pitch 72 = 144 B
  __shared__ __align__(16) _Float16 xsl[2 * 96 * 72];

  float pool[12];
  #pragma unroll
  for (int p = 0; p < 12; ++p) pool[p] = 0.f;

  #pragma unroll
  for (int r = 0; r < 2; ++r) {
    const float* xr = x + ((size_t)(b * 64 + c) * 96 + 2 * rp + r) * 96 + q * 24;
    #pragma unroll
    for (int j2 = 0; j2 < 6; ++j2) {
      f32x4 v = *(const f32x4*)(xr + j2 * 4);
      #pragma unroll
      for (int u = 0; u < 4; ++u) {
        int C = q * 24 + j2 * 4 + u;
        _Float16 hi = (_Float16)v[u];
        xst[(r * 96 + C) * 72 + c] = hi;
        xsl[(r * 96 + C) * 72 + c] = (_Float16)(v[u] - (float)hi);
        pool[(j2 * 4 + u) >> 1] += v[u];
      }
    }
  }
  {
    const int f1 = rp >= 24 ? 1 : 0, wl = rp - f1 * 24;
    #pragma unroll
    for (int p = 0; p < 12; ++p) {
      int C = q * 24 + 2 * p;
      int f2 = C >= 48 ? 1 : 0;
      int m = wl * 24 + (C - f2 * 48) / 2;
      xsum[((size_t)(b * 4 + f1 * 2 + f2) * 576 + m) * 64 + c] = 0.25f * pool[p];
    }
  }
  __syncthreads();
  for (int i = t; i < 1536; i += 256) {
    int r = i / 768, rem = i % 768, col = rem >> 3, cg = rem & 7;
    size_t gdst = (((size_t)b * 96 + 2 * rp + r) * 96 + col) * 64 + cg * 8;
    *(f16x8*)(xt16 + gdst) = *(const f16x8*)&xst[(r * 96 + col) * 72 + cg * 8];
    *(f16x8*)(xlo16 + gdst) = *(const f16x8*)&xsl[(r * 96 + col) * 72 + cg * 8];
  }
}

// ---------------------------------------------------------------------------
// K1b: per (m-chunk of 96, bf): centers via MFMA (3-term hi/lo split),
//   in-register norm reduce, cenW written in K2's fragment-major layout.
// ---------------------------------------------------------------------------
__global__ __launch_bounds__(256) void k1b_centers(
    const float* __restrict__ xsum, const float* __restrict__ b_f,
    const _Float16* __restrict__ wfA, const _Float16* __restrict__ wfT,
    _Float16* __restrict__ cenW, float* __restrict__ dvec)
{
  const int mc = blockIdx.x;          // 0..5
  const int bf = blockIdx.y;          // 0..63
  const int m0 = mc * 96;
  const int t = threadIdx.x;
  const int lane = t & 63, wid = t >> 6;
  const int ccol = lane & 15, g = lane >> 4;

  __shared__ __align__(16) _Float16 cenT_h[96][136];
  __shared__ __align__(16) _Float16 cenT_l[96][136];
  __shared__ __align__(16) _Float16 xcs_h[96][72];
  __shared__ __align__(16) _Float16 xcs_l[96][72];
  float* part = (float*)&xcs_h[0][0];   // aliased after GEMM1 (sync-guarded)

  for (int i = t; i < 96 * 64; i += 256) {
    int m = i >> 6, c = i & 63;
    float s = xsum[((size_t)bf * 576 + m0 + m) * 64 + c];
    _Float16 hi = (_Float16)s;
    xcs_h[m][c] = hi;
    xcs_l[m][c] = (_Float16)(s - (float)hi);
  }
  __syncthreads();

  f32x4 acc[2][6];
  f32x4 bfv[2];
  #pragma unroll
  for (int cbi = 0; cbi < 2; ++cbi) {
    const int cb = wid + cbi * 4;
    bfv[cbi] = *(const f32x4*)(b_f + cb * 16 + g * 4);
    const _Float16* wa = wfA + (size_t)cb * 2048 + (size_t)lane * 8;
    f16x8 a0h = *(const f16x8*)(wa);
    f16x8 a1h = *(const f16x8*)(wa + 512);
    f16x8 a0l = *(const f16x8*)(wa + 1024);
    f16x8 a1l = *(const f16x8*)(wa + 1536);
    #pragma unroll
    for (int nb = 0; nb < 6; ++nb) {
      const int m = nb * 16 + ccol;
      f16x8 b0h = *(const f16x8*)&xcs_h[m][g * 8];
      f16x8 b1h = *(const f16x8*)&xcs_h[m][32 + g * 8];
      f16x8 b0l = *(const f16x8*)&xcs_l[m][g * 8];
      f16x8 b1l = *(const f16x8*)&xcs_l[m][32 + g * 8];
      f32x4 a2 = bfv[cbi];
      a2 = __builtin_amdgcn_mfma_f32_16x16x32_f16(a0h, b0h, a2, 0, 0, 0);
      a2 = __builtin_amdgcn_mfma_f32_16x16x32_f16(a1h, b1h, a2, 0, 0, 0);
      a2 = __builtin_amdgcn_mfma_f32_16x16x32_f16(a0h, b0l, a2, 0, 0, 0);
      a2 = __builtin_amdgcn_mfma_f32_16x16x32_f16(a1h, b1l, a2, 0, 0, 0);
      a2 = __builtin_amdgcn_mfma_f32_16x16x32_f16(a0l, b0h, a2, 0, 0, 0);
      a2 = __builtin_amdgcn_mfma_f32_16x16x32_f16(a1l, b1h, a2, 0, 0, 0);
      acc[cbi][nb] = a2;
    }
  }
  __syncthreads();   // all xcs reads complete; part may now alias it

  #pragma unroll
  for (int nb = 0; nb < 6; ++nb) {
    float ss = 0.f, db = 0.f;
    #pragma unroll
    for (int cbi = 0; cbi < 2; ++cbi)
      #pragma unroll
      for (int r = 0; r < 4; ++r) {
        float v = acc[cbi][nb][r];
        ss = fmaf(v, v, ss);
        db = fmaf(v, bfv[cbi][r], db);
      }
    #pragma unroll
    for (int off = 16; off <= 32; off <<= 1) {
      ss += __shfl_xor(ss, off, 64);
      db += __shfl_xor(db, off, 64);
    }
    if (lane < 16) {
      part[wid * 96 + nb * 16 + lane] = ss;
      part[384 + wid * 96 + nb * 16 + lane] = db;
    }
  }
  __syncthreads();
  if (t < 96) {
    float ss = part[t] + part[96 + t] + part[192 + t] + part[288 + t];
    float db = part[384 + t] + part[480 + t] + part[576 + t] + part[672 + t];
    float inv = 1.0f / fmaxf(sqrtf(ss), 1e-12f);
    part[768 + t] = inv;
    dvec[bf * 576 + m0 + t] = inv * db;
  }
  __syncthreads();

  #pragma unroll
  for (int nb = 0; nb < 6; ++nb) {
    const int m = nb * 16 + ccol;
    const float inv = part[768 + m];
    #pragma unroll
    for (int cbi = 0; cbi < 2; ++cbi) {
      const int cb = wid + cbi * 4;
      #pragma unroll
      for (int r = 0; r < 4; ++r) {
        float v = acc[cbi][nb][r] * inv;
        _Float16 hi = (_Float16)v;
        cenT_h[m][cb * 16 + g * 4 + r] = hi;
        cenT_l[m][cb * 16 + g * 4 + r] = (_Float16)(v - (float)hi);
      }
    }
  }
  __syncthreads();

  // GEMM2: wave wid owns c-block wid; B = wfT frags (global, coalesced)
  const _Float16* wt = wfT + (size_t)wid * 4096 + (size_t)lane * 8;
  f16x8 tbh[4], tbl[4];
  #pragma unroll
  for (int j2 = 0; j2 < 4; ++j2) {
    tbh[j2] = *(const f16x8*)(wt + j2 * 512);
    tbl[j2] = *(const f16x8*)(wt + (j2 + 4) * 512);
  }
  #pragma unroll 1
  for (int mb = 0; mb < 6; ++mb) {
    f16x8 tah[4], tal[4];
    #pragma unroll
    for (int j2 = 0; j2 < 4; ++j2) {
      tah[j2] = *(const f16x8*)&cenT_h[mb * 16 + ccol][j2 * 32 + g * 8];
      tal[j2] = *(const f16x8*)&cenT_l[mb * 16 + ccol][j2 * 32 + g * 8];
    }
    f32x4 a2 = {0.f, 0.f, 0.f, 0.f};
    #pragma unroll
    for (int j2 = 0; j2 < 4; ++j2) {
      a2 = __builtin_amdgcn_mfma_f32_16x16x32_f16(tah[j2], tbh[j2], a2, 0, 0, 0);
      a2 = __builtin_amdgcn_mfma_f32_16x16x32_f16(tah[j2], tbl[j2], a2, 0, 0, 0);
      a2 = __builtin_amdgcn_mfma_f32_16x16x32_f16(tal[j2], tbh[j2], a2, 0, 0, 0);
    }
    const int c = wid * 16 + ccol;
    const int lane2g = ((c >> 3) & 3) << 4;
    const int j2f = c >> 5, e = c & 7;
    #pragma unroll
    for (int r = 0; r < 4; ++r) {
      float v = a2[r];
      _Float16 hi = (_Float16)v;
      _Float16 lo = (_Float16)(v - (float)hi);
      size_t base = (((size_t)bf * 36 + mc * 6 + mb) * 4) * 512
                  + (size_t)((g * 4 + r) | lane2g) * 8 + e;
      cenW[base + (size_t)j2f * 512] = hi;
      cenW[base + (size_t)(j2f + 2) * 512] = lo;
    }
  }
}

// ---------------------------------------------------------------------------
// K2: per (bf, 64-point tile = 4 rows x 16 cols), grid 2304 (9 blocks/CU).
//   Wave wid owns ALL 4 n-blocks (4-chain ILP) and mb range [wid*9, wid*9+9)
//   -> zero intra-block A redundancy, 2x grid depth. 4-wave lexicographic
//   fold in ascending-mb order (bit-identical to single sweep). B-hi from
//   LDS xh (staged coalesced from xt16), B-lo direct from xlo16 global,
//   gather hi-only from xh. Chain-accumulate, strict-> argmax, 2-deep
//   ping-pong with always-valid prefetch + tail body.
// ---------------------------------------------------------------------------
__global__ __launch_bounds__(256, 4) void k2_assign(
    const _Float16* __restrict__ xt16, const _Float16* __restrict__ xlo16,
    const _Float16* __restrict__ cenW,
    const float* __restrict__ dvec,
    float* __restrict__ xsum, float* __restrict__ counts)
{
  const int id = blockIdx.x;          // 0..2303
  const int xcd = id & 7;
  const int j = id >> 3;              // 0..287
  const int bf = xcd * 8 + j / 36;
  const int tile = j % 36;
  const int b = bf >> 2, f1 = (bf >> 1) & 1, f2 = bf & 1;
  const int t = threadIdx.x;
  const int lane = t & 63, wid = t >> 6;

  const int tr = tile / 3, tc = tile % 3;   // tr 0..11 (4 rows), tc 0..2 (16 cols)
  const int w0 = tr * 4, h0 = tc * 16;

  __shared__ __align__(16) _Float16 xh[64][72];
  __shared__ __align__(16) float dvl[576];
  __shared__ float wbv[4][64];
  __shared__ int   wbi[4][64];
  __shared__ int   idxf[64];
  __shared__ int   olist[64];
  __shared__ int   ocnt;

  if (t == 0) ocnt = 0;
  for (int i = t; i < 576; i += 256) dvl[i] = dvec[bf * 576 + i];

  // tile base in xt16/xlo16: [b][R][C][c]; point p = row*16+col,
  // row = p>>4 (0..3), col = p&15; global offset = row*6144 + col*64
  const size_t tbase = (((size_t)b * 96 + f1 * 48 + w0) * 96 + f2 * 48 + h0) * 64;

  // stage hi tile: 512 f16x8 chunks, coalesced
  for (int i = t; i < 512; i += 256) {
    int jj = i >> 3, cg = i & 7;
    f16x8 v = *(const f16x8*)(xt16 + tbase
                + ((size_t)(jj >> 4) * 96 + (jj & 15)) * 64 + cg * 8);
    *(f16x8*)&xh[jj][cg * 8] = v;
  }

  const int ccol = lane & 15;
  const int g = lane >> 4;

  // B-lo fragments direct from global (row q = n-block, contiguous 2KB)
  f16x8 Bl0[4], Bl1[4];
  #pragma unroll
  for (int q = 0; q < 4; ++q) {
    const size_t po = tbase + (size_t)q * 6144 + (size_t)ccol * 64 + g * 8;
    Bl0[q] = *(const f16x8*)(xlo16 + po);
    Bl1[q] = *(const f16x8*)(xlo16 + po + 32);
  }
  __syncthreads();

  // B-hi fragments from LDS
  f16x8 Bh0[4], Bh1[4];
  #pragma unroll
  for (int q = 0; q < 4; ++q) {
    const int p = q * 16 + ccol;
    Bh0[q] = *(const f16x8*)&xh[p][g * 8];
    Bh1[q] = *(const f16x8*)&xh[p][32 + g * 8];
  }

  const int mb0 = wid * 9;            // wave's mb range: [mb0, mb0+9)
  const _Float16* abase = cenW + (size_t)bf * 73728 + (size_t)mb0 * 2048
                        + (size_t)lane * 8;

  float bv[4];
  int bi[4];
  #pragma unroll
  for (int q = 0; q < 4; ++q) { bv[q] = -3.0e38f; bi[q] = 0; }

  f16x8 aA0, aA1, aA2, aA3, aB0, aB1, aB2, aB3;

#define LDA_A(kk) { const _Float16* pa_ = abase + (size_t)(kk) * 2048;       \
    aA0 = *(const f16x8*)(pa_);        aA1 = *(const f16x8*)(pa_ + 512);     \
    aA2 = *(const f16x8*)(pa_ + 1024); aA3 = *(const f16x8*)(pa_ + 1536); }
#define LDA_B(kk) { const _Float16* pb_ = abase + (size_t)(kk) * 2048;       \
    aB0 = *(const f16x8*)(pb_);        aB1 = *(const f16x8*)(pb_ + 512);     \
    aB2 = *(const f16x8*)(pb_ + 1024); aB3 = *(const f16x8*)(pb_ + 1536); }

#define K2_BODY(kk, A0, A1, A2, A3)                                          \
  {                                                                          \
    const int mb = mb0 + (kk);                                               \
    f32x4 dv4 = *(const f32x4*)&dvl[mb * 16 + g * 4];                        \
    _Pragma("unroll")                                                        \
    for (int q = 0; q < 4; ++q) {                                            \
      f32x4 a4 = dv4;                                                        \
      a4 = __builtin_amdgcn_mfma_f32_16x16x32_f16(A0, Bh0[q], a4, 0, 0, 0);  \
      a4 = __builtin_amdgcn_mfma_f32_16x16x32_f16(A1, Bh1[q], a4, 0, 0, 0);  \
      a4 = __builtin_amdgcn_mfma_f32_16x16x32_f16(A0, Bl0[q], a4, 0, 0, 0);  \
      a4 = __builtin_amdgcn_mfma_f32_16x16x32_f16(A1, Bl1[q], a4, 0, 0, 0);  \
      a4 = __builtin_amdgcn_mfma_f32_16x16x32_f16(A2, Bh0[q], a4, 0, 0, 0);  \
      a4 = __builtin_amdgcn_mfma_f32_16x16x32_f16(A3, Bh1[q], a4, 0, 0, 0);  \
      _Pragma("unroll")                                                      \
      for (int r = 0; r < 4; ++r) {                                          \
        float vv = a4[r];                                                    \
        if (vv > bv[q]) { bv[q] = vv; bi[q] = mb * 16 + g * 4 + r; }         \
      }                                                                      \
    }                                                                        \
  }

  LDA_A(0)
  #pragma unroll 1
  for (int k = 0; k < 8; k += 2) {
    LDA_B(k + 1)
    K2_BODY(k, aA0, aA1, aA2, aA3);
    LDA_A(k + 2)                       // k+2 <= 8, always valid
    K2_BODY(k + 1, aB0, aB1, aB2, aB3);
  }
  K2_BODY(8, aA0, aA1, aA2, aA3);      // tail (9th iteration)
#undef K2_BODY
#undef LDA_A
#undef LDA_B

  #pragma unroll
  for (int q = 0; q < 4; ++q) {
    float v = bv[q]; int mi = bi[q];
    #pragma unroll
    for (int off = 16; off <= 32; off <<= 1) {
      float ov = __shfl_xor(v, off, 64);
      int   oi = __shfl_xor(mi, off, 64);
      if (ov > v || (ov == v && oi < mi)) { v = ov; mi = oi; }
    }
    if (lane < 16) { wbv[wid][q * 16 + lane] = v; wbi[wid][q * 16 + lane] = mi; }
  }
  __syncthreads();

  if (t < 64) {
    // fold waves in ascending-mb order (bit-identical to single sweep)
    float v = wbv[0][t]; int mi = wbi[0][t];
    #pragma unroll
    for (int w2 = 1; w2 < 4; ++w2) {
      float ov = wbv[w2][t]; int oi = wbi[w2][t];
      if (ov > v || (ov == v && oi < mi)) { v = ov; mi = oi; }
    }
    idxf[t] = mi;
    int own = (tr * 2 + ((t >> 4) >> 1)) * 24 + tc * 8 + ((t & 15) >> 1);
    if (mi != own) { int o = atomicAdd(&ocnt, 1); olist[o] = t; }
  }
  __syncthreads();

  // ownership gather from LDS xh (hi-only): 16 own centers, 4 per wave
  for (int si = 0; si < 4; ++si) {
    const int s = wid * 4 + si;
    const int r = s >> 3, cq = s & 7;
    const int m = (tr * 2 + r) * 24 + tc * 8 + cq;
    const int p00 = (2 * r) * 16 + 2 * cq;
    float sum = 0.f;
    int cnt = 0;
    #pragma unroll
    for (int dp = 0; dp < 4; ++dp) {
      const int p = p00 + (dp >> 1) * 16 + (dp & 1);
      if (idxf[p] == m) { sum += (float)xh[p][lane]; ++cnt; }
    }
    if (cnt > 0) {
      atomicAdd(&xsum[((size_t)bf * 576 + m) * 64 + lane], sum);
      if (lane == 0) atomicAdd(&counts[bf * 576 + m], (float)cnt);
    }
  }

  for (int o = wid; o < ocnt; o += 4) {
    const int p = olist[o];
    const int m = idxf[p];
    atomicAdd(&xsum[((size_t)bf * 576 + m) * 64 + lane], (float)xh[p][lane]);
    if (lane == 0) atomicAdd(&counts[bf * 576 + m], 1.0f);
  }
}

// ---------------------------------------------------------------------------
// K2c: pooled GEMM + divide + GroupNorm stats:
//   om[m][co] = (W_v·xsum[m])/(cnt[m]+1) + b_v[co]   (f16 out)
// ---------------------------------------------------------------------------
__global__ __launch_bounds__(256) void k2c_pool(
    const float* __restrict__ xsum,
    const float* __restrict__ counts, const _Float16* __restrict__ w_v_h,
    const float* __restrict__ b_v, _Float16* __restrict__ om,
    float* __restrict__ gn_sum, float* __restrict__ gn_ss)
{
  const int chunk = blockIdx.x;       // 0..3
  const int bf = blockIdx.y;          // 0..63
  const int m0 = chunk * 144;
  const int t = threadIdx.x;
  const int lane = t & 63, wid = t >> 6;

  __shared__ __align__(16) _Float16 bh[144][72];
  __shared__ __align__(16) _Float16 bl[144][72];
  __shared__ float rcp_l[144];

  for (int i = t; i < 144 * 64; i += 256) {
    int mq = i >> 6, c = i & 63;
    size_t gdx = ((size_t)bf * 576 + m0 + mq) * 64 + c;
    float s = xsum[gdx];
    _Float16 hi = (_Float16)s;
    bh[mq][c] = hi;
    bl[mq][c] = (_Float16)(s - (float)hi);
  }
  if (t < 144) rcp_l[t] = 1.0f / (counts[bf * 576 + m0 + t] + 1.0f);
  __syncthreads();

  const int ccol = lane & 15, row0 = (lane >> 4) * 4, c0 = (lane >> 4) * 8;
  float sacc = 0.f, ssacc = 0.f;

  #pragma unroll
  for (int cbi = 0; cbi < 2; ++cbi) {
    const int cb = wid + cbi * 4;
    const size_t abase = (size_t)(cb * 16 + ccol) * 64;
    f16x8 a0 = *(const f16x8*)(w_v_h + abase + c0);
    f16x8 a1 = *(const f16x8*)(w_v_h + abase + 32 + c0);
    float bvv[4];
    #pragma unroll
    for (int r = 0; r < 4; ++r) bvv[r] = b_v[cb * 16 + row0 + r];
    for (int nb = 0; nb < 9; ++nb) {
      int mq = nb * 16 + ccol;
      f16x8 bh0 = *(const f16x8*)(&bh[mq][c0]);
      f16x8 bh1 = *(const f16x8*)(&bh[mq][32 + c0]);
      f16x8 bl0 = *(const f16x8*)(&bl[mq][c0]);
      f16x8 bl1 = *(const f16x8*)(&bl[mq][32 + c0]);
      f32x4 a2 = {0.f, 0.f, 0.f, 0.f};
      a2 = __builtin_amdgcn_mfma_f32_16x16x32_f16(a0, bh0, a2, 0, 0, 0);
      a2 = __builtin_amdgcn_mfma_f32_16x16x32_f16(a1, bh1, a2, 0, 0, 0);
      a2 = __builtin_amdgcn_mfma_f32_16x16x32_f16(a0, bl0, a2, 0, 0, 0);
      a2 = __builtin_amdgcn_mfma_f32_16x16x32_f16(a1, bl1, a2, 0, 0, 0);
      float rcp = rcp_l[mq];
      f16x4 o4;
      #pragma unroll
      for (int r = 0; r < 4; ++r) {
        float ov = a2[r] * rcp + bvv[r];
        sacc += ov; ssacc += ov * ov;
        o4[r] = (_Float16)ov;
      }
      *(f16x4*)(om + ((size_t)bf * 576 + m0 + mq) * 128 + cb * 16 + row0) = o4;
    }
  }

  #pragma unroll
  for (int off = 1; off < 64; off <<= 1) {
    sacc += __shfl_xor(sacc, off, 64);
    ssacc += __shfl_xor(ssacc, off, 64);
  }
  __shared__ float rs[4], rss[4];
  if (lane == 0) { rs[wid] = sacc; rss[wid] = ssacc; }
  __syncthreads();
  if (t == 0) {
    atomicAdd(gn_sum + (bf >> 2), rs[0] + rs[1] + rs[2] + rs[3]);
    atomicAdd(gn_ss + (bf >> 2), rss[0] + rss[1] + rss[2] + rss[3]);
  }
}

// ---------------------------------------------------------------------------
// K4: per (b, output row o2): skip conv as implicit GEMM, A from
//   fragment-major wsf, B from xt16 staged in LDS with XOR chunk-swizzle;
//   epilogue: GroupNorm apply + unfold + bias + add.
// ---------------------------------------------------------------------------
__global__ __launch_bounds__(256, 4) void k4_final(
    const _Float16* __restrict__ xt16, const _Float16* __restrict__ wsf,
    const float* __restrict__ b_skip, const _Float16* __restrict__ om,
    const float* __restrict__ gn_sum, const float* __restrict__ gn_ss,
    const float* __restrict__ gamma, const float* __restrict__ beta,
    float* __restrict__ out)
{
  const int o2 = blockIdx.x;          // 0..47
  const int b  = blockIdx.y;          // 0..15
  const int t = threadIdx.x;
  const int lane = t & 63, wid = t >> 6;

  __shared__ __align__(16) _Float16 xl[3 * 97 * 64];

  if (t < 96) {
    int rr = t >> 5, h2 = t & 31;
    *(unsigned int*)&xl[(rr * 97) * 64 + h2 * 2] = 0u;
  }
  for (int i = t; i < 2304; i += 256) {
    int rr = i / 768, rem = i % 768, col = rem >> 3, cg = rem & 7;
    int gr = 2 * o2 - 1 + rr;
    f16x8 v = {};
    if (gr >= 0)
      v = *(const f16x8*)(xt16 + (((size_t)b * 96 + gr) * 96 + col) * 64 + cg * 8);
    int colp = col + 1;
    *(f16x8*)&xl[(rr * 97 + colp) * 64 + ((cg ^ (colp & 7)) << 3)] = v;
  }
  __syncthreads();

  const int ccol = lane & 15, g = lane >> 4;
  const int mb0 = wid * 2;

  f32x4 acc[2][3] = {};
  const int o3a = ccol;

  #pragma unroll 1
  for (int kc = 0; kc < 6; ++kc) {
    f16x8 A[2][3];
    #pragma unroll
    for (int m2 = 0; m2 < 2; ++m2)
      #pragma unroll
      for (int kq = 0; kq < 3; ++kq) {
        int ks = kc * 3 + kq;
        A[m2][kq] = *(const f16x8*)(wsf + (((size_t)(mb0 + m2) * 18 + ks) * 64 + lane) * 8);
      }
    #pragma unroll
    for (int nb = 0; nb < 3; ++nb) {
      const int o3 = nb * 16 + o3a;
      f16x8 Bf[3];
      #pragma unroll
      for (int kq = 0; kq < 3; ++kq) {
        int ks = kc * 3 + kq;
        int dd = ks >> 1, dh = dd / 3, dw = dd % 3, ch = ks & 1;
        int colp = 2 * o3 + dw;
        Bf[kq] = *(const f16x8*)&xl[(dh * 97 + colp) * 64
                                    + ((((ch << 2) | g) ^ (colp & 7)) << 3)];
      }
      #pragma unroll
      for (int kq = 0; kq < 3; ++kq) {
        acc[0][nb] = __builtin_amdgcn_mfma_f32_16x16x32_f16(A[0][kq], Bf[kq], acc[0][nb], 0, 0, 0);
        acc[1][nb] = __builtin_amdgcn_mfma_f32_16x16x32_f16(A[1][kq], Bf[kq], acc[1][nb], 0, 0, 0);
      }
    }
  }

  const float Ninv = 1.0f / 294912.0f;
  const float mu = gn_sum[b] * Ninv;
  const float var = gn_ss[b] * Ninv - mu * mu;
  const float istd = rsqrtf(var + 1e-5f);
  const int f1 = o2 / 24, w24 = o2 % 24;

  #pragma unroll
  for (int m2 = 0; m2 < 2; ++m2) {
    const int mb = mb0 + m2;
    #pragma unroll
    for (int nb = 0; nb < 3; ++nb) {
      const int o3 = nb * 16 + o3a;
      const int f2 = o3 / 24, h = o3 % 24;
      const int bf = b * 4 + f1 * 2 + f2;
      const int m = w24 * 24 + h;
      f16x4 o4 = *(const f16x4*)(om + ((size_t)bf * 576 + m) * 128 + mb * 16 + g * 4);
      #pragma unroll
      for (int r = 0; r < 4; ++r) {
        int co = mb * 16 + g * 4 + r;
        float gnv = ((float)o4[r] - mu) * istd * gamma[co] + beta[co];
        out[((size_t)(b * 128 + co) * 48 + o2) * 48 + o3] = acc[m2][nb][r] + b_skip[co] + gnv;
      }
    }
  }
}

// ---------------------------------------------------------------------------
extern "C" void kernel_launch(void* const* d_in, const int* in_sizes, int n_in,
                              void* d_out, int out_size, void* d_ws, size_t ws_size,
                              hipStream_t stream) {
  const float* x      = (const float*)d_in[0];
  const float* w_f    = (const float*)d_in[1];
  const float* b_f    = (const float*)d_in[2];
  const float* w_v    = (const float*)d_in[3];
  const float* b_v    = (const float*)d_in[4];
  const float* w_skip = (const float*)d_in[5];
  const float* b_skip = (const float*)d_in[6];
  const float* gamma  = (const float*)d_in[7];
  const float* beta   = (const float*)d_in[8];
  float* out = (float*)d_out;

  char* ws = (char*)d_ws;
  _Float16* cenW   = (_Float16*)(ws);                 // 9,437,184 (frag-major hi+lo)
  _Float16* om     = (_Float16*)(ws);                 // aliases cenW (dead after K2)
  float*    dvec   = (float*)(ws + 9437184);          // 147,456
  _Float16* wsf    = (_Float16*)(ws + 9584640);       // 147,456
  _Float16* w_v_h  = (_Float16*)(ws + 9732096);       // 16,384
  float*    xsum   = (float*)(ws + 9748480);          // 9,437,184 (init by K1a)
  float*    counts = (float*)(ws + 19185664);         // 147,456   [memset]
  float*    gn_sum = (float*)(ws + 19333120);         // 256       [memset]
  float*    gn_ss  = (float*)(ws + 19333376);         // 256       [memset]
  _Float16* xt16   = (_Float16*)(ws + 19333632);      // 18,874,368
  _Float16* wfA    = (_Float16*)(ws + 38208000);      // 32,768
  _Float16* wfT    = (_Float16*)(ws + 38240768);      // 32,768
  _Float16* xlo16  = (_Float16*)(ws + 38273536);      // 18,874,368 (end 57,147,904)

  hipMemsetAsync(ws + 19185664, 0, 147968, stream);

  k1a_prep<<<dim3(784), dim3(256), 0, stream>>>(
      x, w_f, w_v, w_skip, xt16, xlo16, xsum, wfA, wfT, w_v_h, wsf);
  k1b_centers<<<dim3(6, 64), dim3(256), 0, stream>>>(
      xsum, b_f, wfA, wfT, cenW, dvec);
  k2_assign<<<dim3(2304), dim3(256), 0, stream>>>(
      xt16, xlo16, cenW, dvec, xsum, counts);
  k2c_pool<<<dim3(4, 64), dim3(256), 0, stream>>>(
      xsum, counts, w_v_h, b_v, om, gn_sum, gn_ss);
  k4_final<<<dim3(48, 16), dim3(256), 0, stream>>>(
      xt16, wsf, b_skip, om, gn_sum, gn_ss, gamma, beta, out);
}